// Round 4
// baseline (685.087 us; speedup 1.0000x reference)
//
#include <hip/hip_runtime.h>
#include <math.h>

#define HIDDEN 4096
#define NEXP   128
#define TOPK   8
#define BT     64                 // tokens per block; grid 256 = 1 block/CU
#define CHUNK  64
#define NCHUNK (HIDDEN / CHUNK)   // 64
#define SSTR   132                // epilogue score row stride (doubles)
#define PLANE  (NEXP * CHUNK)     // 8192 bytes per (chunk,slice) W plane

typedef int v4i __attribute__((ext_vector_type(4)));

static __device__ __forceinline__ unsigned pack4(int a, int b, int c, int d) {
    return (unsigned)(a & 255) | ((unsigned)(b & 255) << 8) |
           ((unsigned)(c & 255) << 16) | ((unsigned)(d & 255) << 24);
}

// Balanced base-128 slicing: val = M * sum_i d_i * 2^(-6-7i), |d_i| <= 64.
// scale1 = 2^13 / M. All float steps exact (pow2 mul, rint, Sterbenz sub).
static __device__ __forceinline__ void slice5(float val, float scale1,
        int& d0, int& d1, int& d2, int& d3, int& d4) {
    float v = val * scale1;
    float f = __builtin_rintf(v);
    float r = v - f;                                 // exact
    int nh = (int)f;                                 // |nh| <= 2^13
    int nl = (int)__builtin_rintf(r * 2097152.0f);   // 2^21, |nl| <= 2^20
    d0 = (nh + 64) >> 7;  d1 = nh - (d0 << 7);
    d2 = (nl + 8192) >> 14;
    int r2 = nl - (d2 << 14);
    d3 = (r2 + 64) >> 7;  d4 = r2 - (d3 << 7);
}

static __device__ __forceinline__ void slice4(float val, float scale1,
        int& d0, int& d1, int& d2, int& d3) {
    float v = val * scale1;
    float f = __builtin_rintf(v);
    float r = v - f;
    int nh = (int)f;
    int nl = (int)__builtin_rintf(r * 16384.0f);     // 2^14, |nl| <= 2^13
    d0 = (nh + 64) >> 7;  d1 = nh - (d0 << 7);
    d2 = (nl + 64) >> 7;  d3 = nl - (d2 << 7);
}

// ---------------- W pre-slicing: [c][s][e][64] i8 planes (2.62 MB) ----------
// (unchanged; router now reads only slices 0..3, plane 4 is simply unread)
__global__ __launch_bounds__(256)
void slice_w_kernel(const float* __restrict__ W, signed char* __restrict__ P)
{
    const int t  = blockIdx.x * 256 + threadIdx.x;   // 65536 threads
    const int e  = t >> 9;
    const int k0 = (t & 511) * 8;
    const float* src = W + (size_t)e * HIDDEN + k0;
    const float4 a = ((const float4*)src)[0];
    const float4 b = ((const float4*)src)[1];

    // M_w = 0.25 -> scale1 = 2^15
    int p00,p01,p02,p03,p04; slice5(a.x, 32768.0f, p00,p01,p02,p03,p04);
    int p10,p11,p12,p13,p14; slice5(a.y, 32768.0f, p10,p11,p12,p13,p14);
    int p20,p21,p22,p23,p24; slice5(a.z, 32768.0f, p20,p21,p22,p23,p24);
    int p30,p31,p32,p33,p34; slice5(a.w, 32768.0f, p30,p31,p32,p33,p34);
    int p40,p41,p42,p43,p44; slice5(b.x, 32768.0f, p40,p41,p42,p43,p44);
    int p50,p51,p52,p53,p54; slice5(b.y, 32768.0f, p50,p51,p52,p53,p54);
    int p60,p61,p62,p63,p64; slice5(b.z, 32768.0f, p60,p61,p62,p63,p64);
    int p70,p71,p72,p73,p74; slice5(b.w, 32768.0f, p70,p71,p72,p73,p74);

    const int c = k0 >> 6, kin = k0 & 63;
    signed char* base = P + ((size_t)(c * 5) * NEXP + e) * CHUNK + kin;
    uint2 v;
    v.x = pack4(p00,p10,p20,p30); v.y = pack4(p40,p50,p60,p70);
    *(uint2*)(base + 0 * PLANE) = v;
    v.x = pack4(p01,p11,p21,p31); v.y = pack4(p41,p51,p61,p71);
    *(uint2*)(base + 1 * PLANE) = v;
    v.x = pack4(p02,p12,p22,p32); v.y = pack4(p42,p52,p62,p72);
    *(uint2*)(base + 2 * PLANE) = v;
    v.x = pack4(p03,p13,p23,p33); v.y = pack4(p43,p53,p63,p73);
    *(uint2*)(base + 3 * PLANE) = v;
    v.x = pack4(p04,p14,p24,p34); v.y = pack4(p44,p54,p64,p74);
    *(uint2*)(base + 4 * PLANE) = v;
}

// Slice 16 consecutive X floats into the 4 packed i8 A-fragments.
static __device__ __forceinline__ void slice_pack16(
        const float4 f0, const float4 f1, const float4 f2, const float4 f3,
        v4i& s0, v4i& s1, v4i& s2, v4i& s3)
{
    unsigned w0[4], w1[4], w2[4], w3[4];
    {
        int a0,b0,c0,d0, a1,b1,c1,d1, a2,b2,c2,d2, a3,b3,c3,d3;
        slice4(f0.x, 1024.0f, a0,a1,a2,a3);
        slice4(f0.y, 1024.0f, b0,b1,b2,b3);
        slice4(f0.z, 1024.0f, c0,c1,c2,c3);
        slice4(f0.w, 1024.0f, d0,d1,d2,d3);
        w0[0] = pack4(a0,b0,c0,d0); w1[0] = pack4(a1,b1,c1,d1);
        w2[0] = pack4(a2,b2,c2,d2); w3[0] = pack4(a3,b3,c3,d3);
    }
    {
        int a0,b0,c0,d0, a1,b1,c1,d1, a2,b2,c2,d2, a3,b3,c3,d3;
        slice4(f1.x, 1024.0f, a0,a1,a2,a3);
        slice4(f1.y, 1024.0f, b0,b1,b2,b3);
        slice4(f1.z, 1024.0f, c0,c1,c2,c3);
        slice4(f1.w, 1024.0f, d0,d1,d2,d3);
        w0[1] = pack4(a0,b0,c0,d0); w1[1] = pack4(a1,b1,c1,d1);
        w2[1] = pack4(a2,b2,c2,d2); w3[1] = pack4(a3,b3,c3,d3);
    }
    {
        int a0,b0,c0,d0, a1,b1,c1,d1, a2,b2,c2,d2, a3,b3,c3,d3;
        slice4(f2.x, 1024.0f, a0,a1,a2,a3);
        slice4(f2.y, 1024.0f, b0,b1,b2,b3);
        slice4(f2.z, 1024.0f, c0,c1,c2,c3);
        slice4(f2.w, 1024.0f, d0,d1,d2,d3);
        w0[2] = pack4(a0,b0,c0,d0); w1[2] = pack4(a1,b1,c1,d1);
        w2[2] = pack4(a2,b2,c2,d2); w3[2] = pack4(a3,b3,c3,d3);
    }
    {
        int a0,b0,c0,d0, a1,b1,c1,d1, a2,b2,c2,d2, a3,b3,c3,d3;
        slice4(f3.x, 1024.0f, a0,a1,a2,a3);
        slice4(f3.y, 1024.0f, b0,b1,b2,b3);
        slice4(f3.z, 1024.0f, c0,c1,c2,c3);
        slice4(f3.w, 1024.0f, d0,d1,d2,d3);
        w0[3] = pack4(a0,b0,c0,d0); w1[3] = pack4(a1,b1,c1,d1);
        w2[3] = pack4(a2,b2,c2,d2); w3[3] = pack4(a3,b3,c3,d3);
    }
    s0 = (v4i){(int)w0[0], (int)w0[1], (int)w0[2], (int)w0[3]};
    s1 = (v4i){(int)w1[0], (int)w1[1], (int)w1[2], (int)w1[3]};
    s2 = (v4i){(int)w2[0], (int)w2[1], (int)w2[2], (int)w2[3]};
    s3 = (v4i){(int)w3[0], (int)w3[1], (int)w3[2], (int)w3[3]};
}

// ---------------- main router kernel ---------------------------------------
// 1 block/CU (grid 256, 256 thr, 1 wave/SIMD, VGPR cap 512). Wave w:
// token-32-group tpair=w&1, expert-64-group ehalf=w>>1 -> Ra=Rb=2.
// Barrier-free K-loop, software-pipelined: slice X[c+1] (VALU) interleaves
// with MFMAs of chunk c (independent -> one basic block). B: 4 digit planes,
// 13-MFMA pyramid (dropped (a0,b4): realistic error ~2^-21).
__global__ __launch_bounds__(256, 1)
void router_kernel(const float* __restrict__ X,
                   const signed char* __restrict__ P,
                   const float* __restrict__ Bias,
                   float* __restrict__ Out, int T)
{
    __shared__ double S[BT * SSTR];   // 64*132*8 = 67584 B, epilogue only

    const int tid  = threadIdx.x;
    const int lane = tid & 63;
    const int wave = tid >> 6;        // 0..3
    const int tokBase = blockIdx.x * BT;

    const int m = lane & 15;          // row/expert within 16-tile
    const int q = lane >> 4;          // k-quarter (16 floats)
    const int tpair = wave & 1;       // token 32-group
    const int ehalf = wave >> 1;      // expert 64-group

    int r0 = tokBase + tpair * 32 + m;      if (r0 >= T) r0 = T - 1;
    int r1 = tokBase + tpair * 32 + 16 + m; if (r1 >= T) r1 = T - 1;
    const float* xp0 = X + (size_t)r0 * HIDDEN + q * 16;
    const float* xp1 = X + (size_t)r1 * HIDDEN + q * 16;

    // B offset: expert = ehalf*64 + et*16 + m, k-quarter q (16 B per lane)
    const size_t boffBase = (size_t)(ehalf * 64 + m) * CHUNK + (size_t)q * 16;

    v4i acc[2][4][5];
    #pragma unroll
    for (int tt = 0; tt < 2; tt++)
        #pragma unroll
        for (int et = 0; et < 4; et++)
            #pragma unroll
            for (int s = 0; s < 5; s++)
                acc[tt][et][s] = (v4i){0, 0, 0, 0};

    // ---- prologue: load X[0], slice -> aC; load X[1] -> xn ----------------
    v4i aC[2][4];
    float4 xn[8];
    {
        const float4* x0 = (const float4*)xp0;
        const float4* x1 = (const float4*)xp1;
        const float4 c0 = x0[0], c1 = x0[1], c2 = x0[2], c3 = x0[3];
        const float4 c4 = x1[0], c5 = x1[1], c6 = x1[2], c7 = x1[3];
        slice_pack16(c0, c1, c2, c3, aC[0][0], aC[0][1], aC[0][2], aC[0][3]);
        slice_pack16(c4, c5, c6, c7, aC[1][0], aC[1][1], aC[1][2], aC[1][3]);
        const float4* y0 = (const float4*)(xp0 + CHUNK);
        const float4* y1 = (const float4*)(xp1 + CHUNK);
        xn[0] = y0[0]; xn[1] = y0[1]; xn[2] = y0[2]; xn[3] = y0[3];
        xn[4] = y1[0]; xn[5] = y1[1]; xn[6] = y1[2]; xn[7] = y1[3];
    }

    #pragma unroll 1
    for (int c = 0; c < NCHUNK; c++) {
        // (1) B loads for chunk c: 4 expert-tiles x 4 slices
        const signed char* pc = P + (size_t)(c * 5) * PLANE;
        v4i B[4][4];
        #pragma unroll
        for (int et = 0; et < 4; et++)
            #pragma unroll
            for (int s = 0; s < 4; s++)
                B[et][s] = *(const v4i*)(pc + (size_t)s * PLANE + boffBase
                                            + (size_t)(et * 16) * CHUNK);

        // (2) X loads for chunk c+2 (wrap-clamped: branch-free, always valid)
        float4 x2[8];
        {
            const int cn = (c + 2) & (NCHUNK - 1);
            const float4* y0 = (const float4*)(xp0 + cn * CHUNK);
            const float4* y1 = (const float4*)(xp1 + cn * CHUNK);
            x2[0] = y0[0]; x2[1] = y0[1]; x2[2] = y0[2]; x2[3] = y0[3];
            x2[4] = y1[0]; x2[5] = y1[1]; x2[6] = y1[2]; x2[7] = y1[3];
        }

        // (3) slice X[c+1] -> aN (independent of this chunk's MFMAs:
        //     scheduler interleaves this VALU with the MFMA block below)
        v4i aN[2][4];
        slice_pack16(xn[0], xn[1], xn[2], xn[3], aN[0][0], aN[0][1], aN[0][2], aN[0][3]);
        slice_pack16(xn[4], xn[5], xn[6], xn[7], aN[1][0], aN[1][1], aN[1][2], aN[1][3]);

        // (4) 13-MFMA pyramid per (tt,et) on chunk c
        #pragma unroll
        for (int tt = 0; tt < 2; tt++) {
            const v4i A0 = aC[tt][0];
            const v4i A1 = aC[tt][1];
            const v4i A2 = aC[tt][2];
            const v4i A3 = aC[tt][3];
            #pragma unroll
            for (int et = 0; et < 4; et++) {
                const v4i B0 = B[et][0];
                const v4i B1 = B[et][1];
                const v4i B2 = B[et][2];
                const v4i B3 = B[et][3];
                acc[tt][et][0] = __builtin_amdgcn_mfma_i32_16x16x64_i8(A0, B0, acc[tt][et][0], 0, 0, 0);
                acc[tt][et][1] = __builtin_amdgcn_mfma_i32_16x16x64_i8(A0, B1, acc[tt][et][1], 0, 0, 0);
                acc[tt][et][1] = __builtin_amdgcn_mfma_i32_16x16x64_i8(A1, B0, acc[tt][et][1], 0, 0, 0);
                acc[tt][et][2] = __builtin_amdgcn_mfma_i32_16x16x64_i8(A0, B2, acc[tt][et][2], 0, 0, 0);
                acc[tt][et][2] = __builtin_amdgcn_mfma_i32_16x16x64_i8(A1, B1, acc[tt][et][2], 0, 0, 0);
                acc[tt][et][2] = __builtin_amdgcn_mfma_i32_16x16x64_i8(A2, B0, acc[tt][et][2], 0, 0, 0);
                acc[tt][et][3] = __builtin_amdgcn_mfma_i32_16x16x64_i8(A0, B3, acc[tt][et][3], 0, 0, 0);
                acc[tt][et][3] = __builtin_amdgcn_mfma_i32_16x16x64_i8(A1, B2, acc[tt][et][3], 0, 0, 0);
                acc[tt][et][3] = __builtin_amdgcn_mfma_i32_16x16x64_i8(A2, B1, acc[tt][et][3], 0, 0, 0);
                acc[tt][et][3] = __builtin_amdgcn_mfma_i32_16x16x64_i8(A3, B0, acc[tt][et][3], 0, 0, 0);
                acc[tt][et][4] = __builtin_amdgcn_mfma_i32_16x16x64_i8(A1, B3, acc[tt][et][4], 0, 0, 0);
                acc[tt][et][4] = __builtin_amdgcn_mfma_i32_16x16x64_i8(A2, B2, acc[tt][et][4], 0, 0, 0);
                acc[tt][et][4] = __builtin_amdgcn_mfma_i32_16x16x64_i8(A3, B1, acc[tt][et][4], 0, 0, 0);
            }
        }

        // (5) rotate pipeline registers
        #pragma unroll
        for (int i = 0; i < 2; i++)
            #pragma unroll
            for (int s = 0; s < 4; s++)
                aC[i][s] = aN[i][s];
        #pragma unroll
        for (int i = 0; i < 8; i++)
            xn[i] = x2[i];
    }

    // ---- epilogue: exact f64 digit combine, sigmoid + bias -> LDS ----------
    {
        const double w0 = 0x1p-11, w1 = 0x1p-18, w2 = 0x1p-25, w3 = 0x1p-32, w4 = 0x1p-39;
        #pragma unroll
        for (int tt = 0; tt < 2; tt++)
            #pragma unroll
            for (int et = 0; et < 4; et++) {
                const int ecol = ehalf * 64 + et * 16 + m;
                const double bias = (double)Bias[ecol];
                #pragma unroll
                for (int r = 0; r < 4; r++) {
                    const int trow = tpair * 32 + tt * 16 + q * 4 + r;
                    const double logit = (double)acc[tt][et][0][r] * w0
                                       + (double)acc[tt][et][1][r] * w1
                                       + (double)acc[tt][et][2][r] * w2
                                       + (double)acc[tt][et][3][r] * w3
                                       + (double)acc[tt][et][4][r] * w4;
                    S[trow * SSTR + ecol] = 1.0 / (1.0 + exp(-logit)) + bias;
                }
            }
    }
    __syncthreads();

    // ---- parallel top-8: 4 lanes per token, stable (lowest index on ties) --
    {
        const int tk  = tid >> 2;        // token within block: 0..63
        const int j   = tid & 3;         // 32-expert group:    0..3
        const int tok = tokBase + tk;
        const double* row = S + tk * SSTR + j * 32;
        double v[32];
        #pragma unroll
        for (int k = 0; k < 32; k++) v[k] = row[k];

        double wts[TOPK]; float idxf[TOPK];
        double wsum = 0.0;
        #pragma unroll
        for (int p = 0; p < TOPK; p++) {
            // local argmax over 32 (ascending strict > -> lowest index wins)
            double best = v[0]; int bi = 0;
            #pragma unroll
            for (int k = 1; k < 32; k++)
                if (v[k] > best) { best = v[k]; bi = k; }
            int be = j * 32 + bi;
            // 4-lane butterfly argmax; tie -> lower expert index
            #pragma unroll
            for (int off = 1; off < 4; off <<= 1) {
                double ob = __shfl_xor(best, off, 4);
                int    oe = __shfl_xor(be,   off, 4);
                if (ob > best || (ob == best && oe < be)) { best = ob; be = oe; }
            }
            // suppress the winner (static indexing -> cndmask, no scratch)
            const bool own = (be >> 5) == j;
            const int  bl  = be & 31;
            #pragma unroll
            for (int k = 0; k < 32; k++)
                if (own && k == bl) v[k] = -1.0e300;
            const double sg = best - (double)Bias[be];
            wts[p]  = sg;
            wsum   += sg;
            idxf[p] = (float)be;
        }
        if (j == 0 && tok < T) {
            const double inv = 1.0 / (wsum + 1e-20);
            float* oi = Out + (size_t)tok * TOPK;
            float* ow = Out + (size_t)T * TOPK + (size_t)tok * TOPK;
            #pragma unroll
            for (int p = 0; p < TOPK; p++) {
                oi[p] = idxf[p];
                ow[p] = (float)(wts[p] * inv);
            }
        }
    }
}

extern "C" void kernel_launch(void* const* d_in, const int* in_sizes, int n_in,
                              void* d_out, int out_size, void* d_ws, size_t ws_size,
                              hipStream_t stream) {
    const float* X    = (const float*)d_in[0];
    const float* W    = (const float*)d_in[1];
    const float* Bias = (const float*)d_in[2];
    float* Out = (float*)d_out;
    const int T = in_sizes[0] / HIDDEN;
    signed char* P = (signed char*)d_ws;   // 2.62 MB of workspace

    hipLaunchKernelGGL(slice_w_kernel, dim3(NEXP * 512 / 256), dim3(256), 0, stream, W, P);
    hipLaunchKernelGGL(router_kernel, dim3((T + BT - 1) / BT), dim3(256), 0, stream,
                       X, P, Bias, Out, T);
}

// Round 5
// 417.873 us; speedup vs baseline: 1.6395x; 1.6395x over previous
//
#include <hip/hip_runtime.h>
#include <math.h>

#define HIDDEN 4096
#define NEXP   128
#define TOPK   8
#define BT     32                 // tokens per block; grid 512 = 2 blocks/CU
#define CHUNK  64
#define NCHUNK (HIDDEN / CHUNK)   // 64
#define SSTR   132                // epilogue score row stride (doubles)
#define PLANE  (NEXP * CHUNK)     // 8192 bytes per (chunk,slice) W plane

typedef int v4i __attribute__((ext_vector_type(4)));

static __device__ __forceinline__ unsigned pack4(int a, int b, int c, int d) {
    return (unsigned)(a & 255) | ((unsigned)(b & 255) << 8) |
           ((unsigned)(c & 255) << 16) | ((unsigned)(d & 255) << 24);
}

// Balanced base-128 slicing: val = M * sum_i d_i * 2^(-6-7i), |d_i| <= 64.
// scale1 = 2^13 / M. All float steps exact (pow2 mul, rint, Sterbenz sub).
static __device__ __forceinline__ void slice5(float val, float scale1,
        int& d0, int& d1, int& d2, int& d3, int& d4) {
    float v = val * scale1;
    float f = __builtin_rintf(v);
    float r = v - f;                                 // exact
    int nh = (int)f;                                 // |nh| <= 2^13
    int nl = (int)__builtin_rintf(r * 2097152.0f);   // 2^21, |nl| <= 2^20
    d0 = (nh + 64) >> 7;  d1 = nh - (d0 << 7);
    d2 = (nl + 8192) >> 14;
    int r2 = nl - (d2 << 14);
    d3 = (r2 + 64) >> 7;  d4 = r2 - (d3 << 7);
}

static __device__ __forceinline__ void slice4(float val, float scale1,
        int& d0, int& d1, int& d2, int& d3) {
    float v = val * scale1;
    float f = __builtin_rintf(v);
    float r = v - f;
    int nh = (int)f;
    int nl = (int)__builtin_rintf(r * 16384.0f);     // 2^14, |nl| <= 2^13
    d0 = (nh + 64) >> 7;  d1 = nh - (d0 << 7);
    d2 = (nl + 64) >> 7;  d3 = nl - (d2 << 7);
}

// ---------------- W pre-slicing: [c][s][e][64] i8 planes (2.62 MB) ----------
// (router reads only slices 0..3; plane 4 is simply unread)
__global__ __launch_bounds__(256)
void slice_w_kernel(const float* __restrict__ W, signed char* __restrict__ P)
{
    const int t  = blockIdx.x * 256 + threadIdx.x;   // 65536 threads
    const int e  = t >> 9;
    const int k0 = (t & 511) * 8;
    const float* src = W + (size_t)e * HIDDEN + k0;
    const float4 a = ((const float4*)src)[0];
    const float4 b = ((const float4*)src)[1];

    // M_w = 0.25 -> scale1 = 2^15
    int p00,p01,p02,p03,p04; slice5(a.x, 32768.0f, p00,p01,p02,p03,p04);
    int p10,p11,p12,p13,p14; slice5(a.y, 32768.0f, p10,p11,p12,p13,p14);
    int p20,p21,p22,p23,p24; slice5(a.z, 32768.0f, p20,p21,p22,p23,p24);
    int p30,p31,p32,p33,p34; slice5(a.w, 32768.0f, p30,p31,p32,p33,p34);
    int p40,p41,p42,p43,p44; slice5(b.x, 32768.0f, p40,p41,p42,p43,p44);
    int p50,p51,p52,p53,p54; slice5(b.y, 32768.0f, p50,p51,p52,p53,p54);
    int p60,p61,p62,p63,p64; slice5(b.z, 32768.0f, p60,p61,p62,p63,p64);
    int p70,p71,p72,p73,p74; slice5(b.w, 32768.0f, p70,p71,p72,p73,p74);

    const int c = k0 >> 6, kin = k0 & 63;
    signed char* base = P + ((size_t)(c * 5) * NEXP + e) * CHUNK + kin;
    uint2 v;
    v.x = pack4(p00,p10,p20,p30); v.y = pack4(p40,p50,p60,p70);
    *(uint2*)(base + 0 * PLANE) = v;
    v.x = pack4(p01,p11,p21,p31); v.y = pack4(p41,p51,p61,p71);
    *(uint2*)(base + 1 * PLANE) = v;
    v.x = pack4(p02,p12,p22,p32); v.y = pack4(p42,p52,p62,p72);
    *(uint2*)(base + 2 * PLANE) = v;
    v.x = pack4(p03,p13,p23,p33); v.y = pack4(p43,p53,p63,p73);
    *(uint2*)(base + 3 * PLANE) = v;
    v.x = pack4(p04,p14,p24,p34); v.y = pack4(p44,p54,p64,p74);
    *(uint2*)(base + 4 * PLANE) = v;
}

// X slicing (M_x = 8 -> scale1 = 2^10): 8 elems -> 4 slice planes of 8 bytes
static __device__ __forceinline__ void slice_store_x(char* dst, float4 xa, float4 xb)
{
    int a00,a01,a02,a03; slice4(xa.x, 1024.0f, a00,a01,a02,a03);
    int a10,a11,a12,a13; slice4(xa.y, 1024.0f, a10,a11,a12,a13);
    int a20,a21,a22,a23; slice4(xa.z, 1024.0f, a20,a21,a22,a23);
    int a30,a31,a32,a33; slice4(xa.w, 1024.0f, a30,a31,a32,a33);
    int a40,a41,a42,a43; slice4(xb.x, 1024.0f, a40,a41,a42,a43);
    int a50,a51,a52,a53; slice4(xb.y, 1024.0f, a50,a51,a52,a53);
    int a60,a61,a62,a63; slice4(xb.z, 1024.0f, a60,a61,a62,a63);
    int a70,a71,a72,a73; slice4(xb.w, 1024.0f, a70,a71,a72,a73);
    uint2 v;
    v.x = pack4(a00,a10,a20,a30); v.y = pack4(a40,a50,a60,a70);
    *(uint2*)(dst + 0 * 2048) = v;
    v.x = pack4(a01,a11,a21,a31); v.y = pack4(a41,a51,a61,a71);
    *(uint2*)(dst + 1 * 2048) = v;
    v.x = pack4(a02,a12,a22,a32); v.y = pack4(a42,a52,a62,a72);
    *(uint2*)(dst + 2 * 2048) = v;
    v.x = pack4(a03,a13,a23,a33); v.y = pack4(a43,a53,a63,a73);
    *(uint2*)(dst + 3 * 2048) = v;
}

// 13-MFMA pyramid per (tt,et): digit pairs with total weight <= 4, minus
// (a0,b4) (B plane 4 dropped; worst-case residual ~2^-15 logit, realistic 2^-21)
#define MFMA13(BF, BUF)                                                        \
    {                                                                          \
        _Pragma("unroll")                                                      \
        for (int tt = 0; tt < 2; tt++) {                                       \
            const char* ap = Ast + (BUF) + (tt ? rph1 : rph0);                 \
            const v4i a0 = *(const v4i*)(ap + 0 * 2048);                       \
            const v4i a1 = *(const v4i*)(ap + 1 * 2048);                       \
            const v4i a2 = *(const v4i*)(ap + 2 * 2048);                       \
            const v4i a3 = *(const v4i*)(ap + 3 * 2048);                       \
            _Pragma("unroll")                                                  \
            for (int et = 0; et < 2; et++) {                                   \
                acc[tt][et][0] = __builtin_amdgcn_mfma_i32_16x16x64_i8(a0, BF[et][0], acc[tt][et][0], 0, 0, 0); \
                acc[tt][et][1] = __builtin_amdgcn_mfma_i32_16x16x64_i8(a0, BF[et][1], acc[tt][et][1], 0, 0, 0); \
                acc[tt][et][1] = __builtin_amdgcn_mfma_i32_16x16x64_i8(a1, BF[et][0], acc[tt][et][1], 0, 0, 0); \
                acc[tt][et][2] = __builtin_amdgcn_mfma_i32_16x16x64_i8(a0, BF[et][2], acc[tt][et][2], 0, 0, 0); \
                acc[tt][et][2] = __builtin_amdgcn_mfma_i32_16x16x64_i8(a1, BF[et][1], acc[tt][et][2], 0, 0, 0); \
                acc[tt][et][2] = __builtin_amdgcn_mfma_i32_16x16x64_i8(a2, BF[et][0], acc[tt][et][2], 0, 0, 0); \
                acc[tt][et][3] = __builtin_amdgcn_mfma_i32_16x16x64_i8(a0, BF[et][3], acc[tt][et][3], 0, 0, 0); \
                acc[tt][et][3] = __builtin_amdgcn_mfma_i32_16x16x64_i8(a1, BF[et][2], acc[tt][et][3], 0, 0, 0); \
                acc[tt][et][3] = __builtin_amdgcn_mfma_i32_16x16x64_i8(a2, BF[et][1], acc[tt][et][3], 0, 0, 0); \
                acc[tt][et][3] = __builtin_amdgcn_mfma_i32_16x16x64_i8(a3, BF[et][0], acc[tt][et][3], 0, 0, 0); \
                acc[tt][et][4] = __builtin_amdgcn_mfma_i32_16x16x64_i8(a1, BF[et][3], acc[tt][et][4], 0, 0, 0); \
                acc[tt][et][4] = __builtin_amdgcn_mfma_i32_16x16x64_i8(a2, BF[et][2], acc[tt][et][4], 0, 0, 0); \
                acc[tt][et][4] = __builtin_amdgcn_mfma_i32_16x16x64_i8(a3, BF[et][1], acc[tt][et][4], 0, 0, 0); \
            }                                                                  \
        }                                                                      \
    }

// ---------------- main router kernel ---------------------------------------
// R0 structure (LDS A-exchange, Ra=1, 2 blocks/CU) but with RAW s_barrier +
// lgkmcnt(0)-only drain: the next chunk's B-register and X-float loads stay
// in flight across the barrier (counted vmcnt, T3/T4 pattern). Manual 2x
// unroll ping-pongs B/X registers so no moves touch in-flight loads.
__global__ __launch_bounds__(256, 2)
void router_kernel(const float* __restrict__ X,
                   const signed char* __restrict__ P,
                   const float* __restrict__ Bias,
                   float* __restrict__ Out, int T)
{
    __shared__ double S[BT * SSTR];   // 33792 B; first 16 KB doubles as A staging
    char* Ast = (char*)S;             // [buf 8192][slice 2048][unit 16]

    const int tid  = threadIdx.x;
    const int lane = tid & 63;
    const int wave = tid >> 6;
    const int tokBase = blockIdx.x * BT;

    // slicing job: token sm, k-run of 8
    const int sm  = tid & 31;
    const int sk8 = tid >> 5;
    int srow = tokBase + sm; if (srow >= T) srow = T - 1;
    const float* xptr = X + (size_t)srow * HIDDEN + sk8 * 8;
    const int su    = sm * 4 + (sk8 >> 1);                    // unit = m*4 + k16
    const int swoff = ((su ^ ((su >> 3) & 7)) << 4) + (sk8 & 1) * 8;

    // A-frag LDS read offsets (m = lane&15, k-quarter = lane>>4)
    const int ru0  = ((lane & 15)     ) * 4 + (lane >> 4);
    const int ru1  = ((lane & 15) + 16) * 4 + (lane >> 4);
    const int rph0 = (ru0 ^ ((ru0 >> 3) & 7)) << 4;
    const int rph1 = (ru1 ^ ((ru1 >> 3) & 7)) << 4;

    // B global offsets (n = lane&15, k-quarter = lane>>4): contiguous 1KB/wave
    const int eb0 = wave * 32 + (lane & 15);
    const int koff = (lane >> 4) * 16;
    const size_t boff0 = (size_t)eb0 * CHUNK + koff;
    const size_t boff1 = boff0 + (size_t)16 * CHUNK;

    v4i acc[2][2][5];
    #pragma unroll
    for (int tt = 0; tt < 2; tt++)
        #pragma unroll
        for (int et = 0; et < 2; et++)
            #pragma unroll
            for (int s = 0; s < 5; s++)
                acc[tt][et][s] = (v4i){0, 0, 0, 0};

    // ---- prologue: slice X[0] -> buf0; issue B[0] and X[1] loads ----------
    {
        float4 xa = ((const float4*)xptr)[0];
        float4 xb = ((const float4*)xptr)[1];
        slice_store_x(Ast + swoff, xa, xb);
    }
    v4i bfE[2][4], bfO[2][4];
    #pragma unroll
    for (int s = 0; s < 4; s++) {
        bfE[0][s] = *(const v4i*)(P + (size_t)s * PLANE + boff0);
        bfE[1][s] = *(const v4i*)(P + (size_t)s * PLANE + boff1);
    }
    float4 xoa = ((const float4*)(xptr + CHUNK))[0];
    float4 xob = ((const float4*)(xptr + CHUNK))[1];

    asm volatile("s_waitcnt lgkmcnt(0)" ::: "memory");
    __builtin_amdgcn_s_barrier();

    float4 xea, xeb;
    #pragma unroll 1
    for (int c = 0; c < NCHUNK; c += 2) {
        // ---- even chunk c: A = buf0, B = bfE; prefetch B[c+1], X[c+2] -----
        {
            const signed char* pn = P + (size_t)((c + 1) * 5) * PLANE;
            #pragma unroll
            for (int s = 0; s < 4; s++) {
                bfO[0][s] = *(const v4i*)(pn + (size_t)s * PLANE + boff0);
                bfO[1][s] = *(const v4i*)(pn + (size_t)s * PLANE + boff1);
            }
            const float* nx = xptr + ((c + 2) & (NCHUNK - 1)) * CHUNK;
            xea = ((const float4*)nx)[0];
            xeb = ((const float4*)nx)[1];

            MFMA13(bfE, 0)

            slice_store_x(Ast + 8192 + swoff, xoa, xob);   // A[c+1] -> buf1
            asm volatile("s_waitcnt lgkmcnt(0)" ::: "memory");
            __builtin_amdgcn_s_barrier();
        }
        // ---- odd chunk c+1: A = buf1, B = bfO; prefetch B[c+2], X[c+3] ----
        {
            const signed char* pn = P + (size_t)(((c + 2) & (NCHUNK - 1)) * 5) * PLANE;
            #pragma unroll
            for (int s = 0; s < 4; s++) {
                bfE[0][s] = *(const v4i*)(pn + (size_t)s * PLANE + boff0);
                bfE[1][s] = *(const v4i*)(pn + (size_t)s * PLANE + boff1);
            }
            const float* nx = xptr + ((c + 3) & (NCHUNK - 1)) * CHUNK;
            xoa = ((const float4*)nx)[0];
            xob = ((const float4*)nx)[1];

            MFMA13(bfO, 8192)

            if (c + 2 < NCHUNK)
                slice_store_x(Ast + swoff, xea, xeb);      // A[c+2] -> buf0
            asm volatile("s_waitcnt lgkmcnt(0)" ::: "memory");
            __builtin_amdgcn_s_barrier();
        }
    }

    // ---- epilogue: exact f64 digit combine, sigmoid + bias -> LDS ----------
    {
        const double w0 = 0x1p-11, w1 = 0x1p-18, w2 = 0x1p-25, w3 = 0x1p-32, w4 = 0x1p-39;
        #pragma unroll
        for (int tt = 0; tt < 2; tt++)
            #pragma unroll
            for (int et = 0; et < 2; et++) {
                const int ecol = wave * 32 + et * 16 + (lane & 15);
                const double bias = (double)Bias[ecol];
                #pragma unroll
                for (int r = 0; r < 4; r++) {
                    const int trow = tt * 16 + (lane >> 4) * 4 + r;
                    const double logit = (double)acc[tt][et][0][r] * w0
                                       + (double)acc[tt][et][1][r] * w1
                                       + (double)acc[tt][et][2][r] * w2
                                       + (double)acc[tt][et][3][r] * w3
                                       + (double)acc[tt][et][4][r] * w4;
                    S[trow * SSTR + ecol] = 1.0 / (1.0 + exp(-logit)) + bias;
                }
            }
    }
    __syncthreads();

    // ---- parallel top-8: 8 lanes per token, stable (lowest index on ties) --
    {
        const int tk  = tid >> 3;        // token within block: 0..31
        const int j   = tid & 7;         // 16-expert group:    0..7
        const int tok = tokBase + tk;
        const double* row = S + tk * SSTR + j * 16;
        double v[16];
        #pragma unroll
        for (int k = 0; k < 16; k++) v[k] = row[k];

        double wts[TOPK]; float idxf[TOPK];
        double wsum = 0.0;
        #pragma unroll
        for (int p = 0; p < TOPK; p++) {
            // local argmax over 16 (ascending strict > -> lowest index wins)
            double best = v[0]; int bi = 0;
            #pragma unroll
            for (int k = 1; k < 16; k++)
                if (v[k] > best) { best = v[k]; bi = k; }
            int be = j * 16 + bi;
            // 8-lane butterfly argmax; tie -> lower expert index
            #pragma unroll
            for (int off = 1; off < 8; off <<= 1) {
                double ob = __shfl_xor(best, off, 8);
                int    oe = __shfl_xor(be,   off, 8);
                if (ob > best || (ob == best && oe < be)) { best = ob; be = oe; }
            }
            // suppress the winner (static indexing -> cndmask, no scratch)
            const bool own = (be >> 4) == j;
            const int  bl  = be & 15;
            #pragma unroll
            for (int k = 0; k < 16; k++)
                if (own && k == bl) v[k] = -1.0e300;
            const double sg = best - (double)Bias[be];
            wts[p]  = sg;
            wsum   += sg;
            idxf[p] = (float)be;
        }
        if (j == 0 && tok < T) {
            const double inv = 1.0 / (wsum + 1e-20);
            float* oi = Out + (size_t)tok * TOPK;
            float* ow = Out + (size_t)T * TOPK + (size_t)tok * TOPK;
            #pragma unroll
            for (int p = 0; p < TOPK; p++) {
                oi[p] = idxf[p];
                ow[p] = (float)(wts[p] * inv);
            }
        }
    }
}

extern "C" void kernel_launch(void* const* d_in, const int* in_sizes, int n_in,
                              void* d_out, int out_size, void* d_ws, size_t ws_size,
                              hipStream_t stream) {
    const float* X    = (const float*)d_in[0];
    const float* W    = (const float*)d_in[1];
    const float* Bias = (const float*)d_in[2];
    float* Out = (float*)d_out;
    const int T = in_sizes[0] / HIDDEN;
    signed char* P = (signed char*)d_ws;   // 2.62 MB of workspace

    hipLaunchKernelGGL(slice_w_kernel, dim3(NEXP * 512 / 256), dim3(256), 0, stream, W, P);
    hipLaunchKernelGGL(router_kernel, dim3((T + BT - 1) / BT), dim3(256), 0, stream,
                       X, P, Bias, Out, T);
}